// Round 4
// baseline (1082.931 us; speedup 1.0000x reference)
//
#include <hip/hip_runtime.h>
#include <hip/hip_bf16.h>
#include <math.h>

#ifndef M_PI
#define M_PI 3.14159265358979323846
#endif

typedef __attribute__((ext_vector_type(8))) short bf16x8;
typedef __attribute__((ext_vector_type(4))) float f32x4;

struct Filt { float f[12]; };

// ---------------------------------------------------------------------------
// Host-side kaiser-sinc filter (matches reference; FILT_UP == FILT_DOWN).
// ---------------------------------------------------------------------------
static double bessel_i0(double x) {
  double sum = 1.0, term = 1.0;
  for (int k = 1; k < 64; ++k) {
    term *= x / (2.0 * k);
    double t2 = term * term;
    sum += t2;
    if (t2 < 1e-22 * sum) break;
  }
  return sum;
}

static void compute_filter(float* out12) {
  const int ks = 12;
  const double cutoff = 0.25, half_width = 0.3;
  const int half_size = 6;
  double delta_f = 4.0 * half_width;
  double A = 2.285 * (half_size - 1) * M_PI * delta_f + 7.95;
  double beta;
  if (A > 50.0)       beta = 0.1102 * (A - 8.7);
  else if (A >= 21.0) beta = 0.5842 * pow(A - 21.0, 0.4) + 0.07886 * (A - 21.0);
  else                beta = 0.0;
  double i0b = bessel_i0(beta);
  double f[12], s = 0.0;
  for (int n = 0; n < ks; ++n) {
    double ratio = (n - (ks - 1) / 2.0) / ((ks - 1) / 2.0);
    double arg = 1.0 - ratio * ratio;
    double wnd = bessel_i0(beta * sqrt(arg > 0.0 ? arg : 0.0)) / i0b;
    double time = (n - half_size) + 0.5;
    double xx = 2.0 * cutoff * time;
    double sinc = (xx == 0.0) ? 1.0 : sin(M_PI * xx) / (M_PI * xx);
    f[n] = 2.0 * cutoff * wnd * sinc;
    s += f[n];
  }
  for (int n = 0; n < ks; ++n) out12[n] = (float)(f[n] / s);
}

__device__ __forceinline__ ushort f2bf(float f) {
  __hip_bfloat16 h = __float2bfloat16(f);
  return *(ushort*)&h;
}

__device__ __forceinline__ void gl_lds16(const void* g, void* l) {
  __builtin_amdgcn_global_load_lds(
      (const __attribute__((address_space(1))) unsigned int*)g,
      (__attribute__((address_space(3))) unsigned int*)l, 16, 0, 0);
}

// ---------------------------------------------------------------------------
// act2: fused upsample(x2,edge) -> snake_beta -> downsample(/2,edge).
// Thread = (channel c, 16 consecutive t). Downsample accumulation is FUSED
// into sb production to kill the sbv[42] register array (R3: 256 VGPRs,
// 10% occupancy). sb pair j=2m,2m+1 (from x window xv[m..m+5]) feeds
// acc[m-5..m] with taps F[2k],F[2k+1], k=m-i:
//   sb[2m]   (p odd):  2*sum_s F[2s+1]*xv[m+s]   -> acc[m-k] += F[2k]*sb
//   sb[2m+1] (p even): 2*sum_s F[2s]  *xv[m+s]   -> acc[m-k] += F[2k+1]*sb
// Edge blocks take a generic clamped path (wave-uniform branches).
// TOUT=true : out bf16 transposed [B][T][C]; TOUT=false: fp32 [B][C][T]+resid.
// ---------------------------------------------------------------------------
template <typename TIN, bool TOUT>
__global__ __launch_bounds__(256) void act2(
    const TIN* __restrict__ in, void* __restrict__ out_,
    const float* __restrict__ alpha_log, const float* __restrict__ beta_log,
    const float* __restrict__ resid, int C, int T, Filt fl)
{
  __shared__ float xs[64 * 75];  // row stride 75 (odd -> conflict-free), 74 used
  const int t0 = blockIdx.x * 64;
  const int c0 = blockIdx.y * 64;
  const int b  = blockIdx.z;
  const int tid = threadIdx.x;

  // Stage x rows: xs[c][j] = x[clamp(t0-5+j)], j<74 (coalesced along t)
  for (int i = tid; i < 64 * 74; i += 256) {
    int c = i / 74, j = i - c * 74;
    int t = min(max(t0 - 5 + j, 0), T - 1);
    xs[c * 75 + j] = (float)in[((long)(b * C + c0 + c)) * T + t];
  }
  __syncthreads();

  const int c  = tid & 63;
  const int tg = tid >> 6;
  const int tb = t0 + tg * 16;
  const float a  = __expf(alpha_log[c0 + c]);
  const float rb = 1.0f / (__expf(beta_log[c0 + c]) + 1e-9f);

  float acc[16];
#pragma unroll
  for (int i = 0; i < 16; ++i) acc[i] = 0.0f;

  const bool interior = (2 * tb - 5 >= 0) && (2 * tb + 36 <= 2 * T - 1);  // wave-uniform
  if (interior) {
    float xv[26];
    const float* xr = xs + c * 75 + tg * 16;  // xv[m] = x[tb-5+m]
#pragma unroll
    for (int m = 0; m < 26; ++m) xv[m] = xr[m];
#pragma unroll
    for (int m = 0; m <= 20; ++m) {
      float uo = fl.f[1] * xv[m]     + fl.f[3] * xv[m + 1] + fl.f[5]  * xv[m + 2]
               + fl.f[7] * xv[m + 3] + fl.f[9] * xv[m + 4] + fl.f[11] * xv[m + 5];
      float ue = fl.f[0] * xv[m]     + fl.f[2] * xv[m + 1] + fl.f[4]  * xv[m + 2]
               + fl.f[6] * xv[m + 3] + fl.f[8] * xv[m + 4] + fl.f[10] * xv[m + 5];
      uo *= 2.0f; ue *= 2.0f;
      float s0 = __sinf(a * uo);
      float s1 = __sinf(a * ue);
      float sb0 = uo + rb * s0 * s0;   // sb slot j=2m
      float sb1 = ue + rb * s1 * s1;   // sb slot j=2m+1
#pragma unroll
      for (int k = 0; k < 6; ++k) {
        int i = m - k;
        if (i >= 0 && i < 16)
          acc[i] += fl.f[2 * k] * sb0 + fl.f[2 * k + 1] * sb1;
      }
    }
  } else {
    const float* xr = xs + c * 75;  // xr[idx] = x[clamp(t0-5+idx)]
#pragma unroll
    for (int j = 0; j < 42; ++j) {
      int p = 2 * tb - 5 + j;
      int pc = min(max(p, 0), 2 * T - 1);
      float up;
      if (pc & 1) {                 // wave-uniform branch (pc indep. of lane)
        int q = (pc - 1) >> 1;
        int base = q - t0 + 3;      // x[q-2]
        up = fl.f[1] * xr[base]     + fl.f[3] * xr[base + 1] + fl.f[5]  * xr[base + 2]
           + fl.f[7] * xr[base + 3] + fl.f[9] * xr[base + 4] + fl.f[11] * xr[base + 5];
      } else {
        int q = pc >> 1;
        int base = q - t0 + 2;      // x[q-3]
        up = fl.f[0] * xr[base]     + fl.f[2] * xr[base + 1] + fl.f[4]  * xr[base + 2]
           + fl.f[6] * xr[base + 3] + fl.f[8] * xr[base + 4] + fl.f[10] * xr[base + 5];
      }
      up *= 2.0f;
      float s = __sinf(a * up);
      float sbj = up + rb * s * s;
#pragma unroll
      for (int i = 0; i < 16; ++i) {
        int u = j - 2 * i;
        if (u >= 0 && u <= 11) acc[i] += fl.f[u] * sbj;
      }
    }
  }

  if constexpr (TOUT) {
    __hip_bfloat16* out = (__hip_bfloat16*)out_;
#pragma unroll
    for (int i = 0; i < 16; ++i)  // lanes = 64 consecutive c -> 128B/instr
      out[((long)b * T + tb + i) * C + c0 + c] = __float2bfloat16(acc[i]);
  } else {
    float* out = (float*)out_;
    __syncthreads();            // all xs reads done before reuse
    float* ys = xs;             // ys[c][tl], stride 65 (odd)
#pragma unroll
    for (int i = 0; i < 16; ++i) ys[c * 65 + tg * 16 + i] = acc[i];
    __syncthreads();
    for (int i = tid; i < 64 * 64; i += 256) {
      int cc = i >> 6, tl = i & 63;
      long o = ((long)(b * C + c0 + cc)) * T + t0 + tl;
      out[o] = ys[cc * 65 + tl] + resid[o];
    }
  }
}

// ---------------------------------------------------------------------------
// Weight pre-conversion: w fp32 [co][ci][3] -> bf16 [d][co][ci]
// ---------------------------------------------------------------------------
__global__ __launch_bounds__(256) void wconv(
    const float* __restrict__ w, ushort* __restrict__ wbf, int C)
{
  int idx = blockIdx.x * 256 + threadIdx.x;
  int total = 3 * C * C;
  if (idx >= total) return;
  int d = idx / (C * C);
  int r = idx - d * C * C;          // co*C + ci
  wbf[idx] = f2bf(w[(long)r * 3 + d]);
}

// ---------------------------------------------------------------------------
// conv_mfma: out[b,co,t] = bias[co] + sum_{ci,d} w[co,ci,d]*in[b,ci,t-1+d]
// (zero pad). Implicit GEMM via mfma_f32_16x16x32_bf16, tap-decomposed.
// Staging pure 16B global_load_lds (full waves, wave-uniform LDS base);
// halo rows (t0-1, t0+NTC) via 8 bounds-checked ds_writes.
// ---------------------------------------------------------------------------
#define MT 64
#define NTC 256
#define BK 32

__global__ __launch_bounds__(256) void conv_mfma(
    const __hip_bfloat16* __restrict__ inT,  // [B][T][C] bf16
    const ushort* __restrict__ wbf,          // [3][C(co)][C(ci)] bf16
    const float* __restrict__ bias,
    __hip_bfloat16* __restrict__ out,        // [B][C][T] bf16
    int C, int T)
{
  __shared__ ushort wl[3][MT][BK];           // slot g=((d*64+co)*4+seg) at byte g*16
  __shared__ ushort xs[NTC + 2][BK];         // slot g=(tl*4+seg) at byte g*16
  const int t0  = blockIdx.x * NTC;
  const int co0 = blockIdx.y * MT;
  const int b   = blockIdx.z;
  const int tid  = threadIdx.x;
  const int lane = tid & 63;
  const int wave = tid >> 6;
  const int ln15 = lane & 15;
  const int quad = lane >> 4;
  const ushort* inU = (const ushort*)inT;

  f32x4 acc[4][4];
#pragma unroll
  for (int mi = 0; mi < 4; ++mi)
#pragma unroll
    for (int ni = 0; ni < 4; ++ni) acc[mi][ni] = (f32x4){0.f, 0.f, 0.f, 0.f};

  ushort* wlf = &wl[0][0][0];
  ushort* xsf = &xs[0][0];

  for (int ci0 = 0; ci0 < C; ci0 += BK) {
    __syncthreads();
    // --- weights: 768 slots of 16B, 3 full-wave iterations
#pragma unroll
    for (int it = 0; it < 3; ++it) {
      int g = it * 256 + tid;
      int d = g >> 8, co = (g >> 2) & 63, seg = g & 3;
      const ushort* gsrc = wbf + ((long)d * C + co0 + co) * C + ci0 + seg * 8;
      gl_lds16(gsrc, wlf + (size_t)(it * 256 + (tid & ~63)) * 8);
    }
    // --- input interior rows tl=1..256 (t always in-bounds): slots 4..1027
#pragma unroll
    for (int it = 0; it < 4; ++it) {
      int g = it * 256 + tid + 4;
      int tl = g >> 2, seg = g & 3;
      int t = t0 - 1 + tl;
      const ushort* gsrc = inU + ((long)b * T + t) * C + ci0 + seg * 8;
      gl_lds16(gsrc, xsf + (size_t)(it * 256 + (tid & ~63) + 4) * 8);
    }
    // --- halo rows tl=0 (t0-1) and tl=257 (t0+NTC), zero-padded
    if (tid < 8) {
      int g = (tid < 4) ? tid : (1028 + tid - 4);
      int tl = g >> 2, seg = g & 3;
      int t = t0 - 1 + tl;
      uint4 v = {0u, 0u, 0u, 0u};
      if (t >= 0 && t < T)
        v = *(const uint4*)(inU + ((long)b * T + t) * C + ci0 + seg * 8);
      *(uint4*)&xs[tl][seg * 8] = v;
    }
    __syncthreads();

#pragma unroll
    for (int d = 0; d < 3; ++d) {
      bf16x8 afr[4], bfr[4];
#pragma unroll
      for (int mi = 0; mi < 4; ++mi)
        afr[mi] = *(const bf16x8*)&wl[d][mi * 16 + ln15][quad * 8];
#pragma unroll
      for (int ni = 0; ni < 4; ++ni)
        bfr[ni] = *(const bf16x8*)&xs[wave * 64 + ni * 16 + ln15 + d][quad * 8];
#pragma unroll
      for (int mi = 0; mi < 4; ++mi)
#pragma unroll
        for (int ni = 0; ni < 4; ++ni)
          acc[mi][ni] = __builtin_amdgcn_mfma_f32_16x16x32_bf16(
              afr[mi], bfr[ni], acc[mi][ni], 0, 0, 0);
    }
  }

  // epilogue: D[m][n]: n(t)=lane&15, m(co)=quad*4+reg
#pragma unroll
  for (int mi = 0; mi < 4; ++mi) {
#pragma unroll
    for (int r = 0; r < 4; ++r) {
      int co = co0 + mi * 16 + quad * 4 + r;
      float bv = bias[co];
      long orow = ((long)(b * C + co)) * T;
#pragma unroll
      for (int ni = 0; ni < 4; ++ni) {
        int t = t0 + wave * 64 + ni * 16 + ln15;
        out[orow + t] = __float2bfloat16(acc[mi][ni][r] + bv);
      }
    }
  }
}

// ---------------------------------------------------------------------------
// Pipeline. Weight bf16 scratch lives in d_out's head (3MB), fully
// overwritten by the final act2 which writes all B*C*T floats.
// ws = 2 x 67MB bf16 ping-pong.
// ---------------------------------------------------------------------------
extern "C" void kernel_launch(void* const* d_in, const int* in_sizes, int n_in,
                              void* d_out, int out_size, void* d_ws, size_t ws_size,
                              hipStream_t stream) {
  const float* x      = (const float*)d_in[0];
  const float* w1     = (const float*)d_in[1];
  const float* b1     = (const float*)d_in[2];
  const float* w2     = (const float*)d_in[3];
  const float* b2     = (const float*)d_in[4];
  const float* alpha1 = (const float*)d_in[5];
  const float* beta1  = (const float*)d_in[6];
  const float* alpha2 = (const float*)d_in[7];
  const float* beta2  = (const float*)d_in[8];
  float* out = (float*)d_out;

  const int C = in_sizes[2];             // 512
  const long total = (long)in_sizes[0];  // B*C*T
  const int T = 8192;
  const int B = (int)(total / ((long)C * T));

  __hip_bfloat16* ws0 = (__hip_bfloat16*)d_ws;        // [B][T][C]
  __hip_bfloat16* ws1 = ws0 + (size_t)B * C * T;      // [B][C][T]
  ushort* w1bf = (ushort*)d_out;                      // scratch in out head
  ushort* w2bf = w1bf + (size_t)3 * C * C;

  Filt fl;
  compute_filter(fl.f);

  dim3 actGrid(T / 64, C / 64, B);
  dim3 convGrid(T / NTC, C / MT, B);
  int wblocks = (3 * C * C + 255) / 256;

  wconv<<<wblocks, 256, 0, stream>>>(w1, w1bf, C);
  wconv<<<wblocks, 256, 0, stream>>>(w2, w2bf, C);
  act2<float, true><<<actGrid, 256, 0, stream>>>(x, ws0, alpha1, beta1, nullptr, C, T, fl);
  conv_mfma<<<convGrid, 256, 0, stream>>>(ws0, w1bf, b1, ws1, C, T);
  act2<__hip_bfloat16, true><<<actGrid, 256, 0, stream>>>(ws1, ws0, alpha1, beta1, nullptr, C, T, fl);
  conv_mfma<<<convGrid, 256, 0, stream>>>(ws0, w2bf, b2, ws1, C, T);
  act2<__hip_bfloat16, false><<<actGrid, 256, 0, stream>>>(ws1, out, alpha2, beta2, x, C, T, fl);
}